// Round 1
// baseline (7639.153 us; speedup 1.0000x reference)
//
#include <hip/hip_runtime.h>
#include <hip/hip_bf16.h>
#include <math.h>

#define BB 2
#define SS 1024
#define HH 2048
#define NHD 16
#define NOPE 128
#define ROPED 64
#define VDIM 128
#define QKD 192
#define QLR 1536
#define KVLR 512
#define EPSF 1e-5f

// ---------------------------------------------------------------------------
// Generic tiled fp32 GEMM.
//   BT = true :  C = A (M,K) * B^T  with B stored (N,K) row-major
//   BT = false:  C = A (M,K) * B    with B stored (K,N) row-major
// lda/ldb/ldc are row strides (elements); sA/sB/sC are grid.z batch strides.
// All M,N multiples of 64 and K multiples of 16 in this problem: no guards.
// ---------------------------------------------------------------------------
template<bool BT>
__global__ __launch_bounds__(256) void gemm_tile(
    const float* __restrict__ A, const float* __restrict__ B, float* __restrict__ C,
    int M, int N, int K, int lda, int ldb, int ldc,
    long long sA, long long sB, long long sC)
{
    __shared__ float As[16][65];
    __shared__ float Bs[16][65];
    const float* Ab = A + (long long)blockIdx.z * sA;
    const float* Bb = B + (long long)blockIdx.z * sB;
    float*       Cb = C + (long long)blockIdx.z * sC;
    int tid = threadIdx.x;
    int tx = tid & 15, ty = tid >> 4;
    int m0 = blockIdx.y * 64, n0 = blockIdx.x * 64;
    float acc[4][4] = {};
    for (int k0 = 0; k0 < K; k0 += 16) {
#pragma unroll
        for (int i = 0; i < 4; ++i) {
            int e = tid + i * 256;
            int m = e >> 4, k = e & 15;
            As[k][m] = Ab[(long long)(m0 + m) * lda + (k0 + k)];
        }
        if (BT) {
#pragma unroll
            for (int i = 0; i < 4; ++i) {
                int e = tid + i * 256;
                int n = e >> 4, k = e & 15;
                Bs[k][n] = Bb[(long long)(n0 + n) * ldb + (k0 + k)];
            }
        } else {
#pragma unroll
            for (int i = 0; i < 4; ++i) {
                int e = tid + i * 256;
                int k = e >> 6, n = e & 63;
                Bs[k][n] = Bb[(long long)(k0 + k) * ldb + (n0 + n)];
            }
        }
        __syncthreads();
#pragma unroll
        for (int kk = 0; kk < 16; ++kk) {
            float a[4], b[4];
#pragma unroll
            for (int i = 0; i < 4; ++i) a[i] = As[kk][ty * 4 + i];
#pragma unroll
            for (int j = 0; j < 4; ++j) b[j] = Bs[kk][tx * 4 + j];
#pragma unroll
            for (int i = 0; i < 4; ++i)
#pragma unroll
                for (int j = 0; j < 4; ++j)
                    acc[i][j] += a[i] * b[j];
        }
        __syncthreads();
    }
#pragma unroll
    for (int i = 0; i < 4; ++i) {
        long long m = m0 + ty * 4 + i;
#pragma unroll
        for (int j = 0; j < 4; ++j)
            Cb[m * ldc + (n0 + tx * 4 + j)] = acc[i][j];
    }
}

// ---------------------------------------------------------------------------
// In-place LayerNorm over last dim N (full LN: mean-subtract), weight w.
// One block (256 thr) per row.
// ---------------------------------------------------------------------------
__global__ __launch_bounds__(256) void ln_kernel(float* __restrict__ x,
                                                 const float* __restrict__ w, int N)
{
    long long row = blockIdx.x;
    float* xr = x + row * N;
    int tid = threadIdx.x;
    float s = 0.f, ss = 0.f;
    for (int i = tid; i < N; i += 256) { float v = xr[i]; s += v; ss += v * v; }
#pragma unroll
    for (int off = 32; off > 0; off >>= 1) { s += __shfl_down(s, off); ss += __shfl_down(ss, off); }
    __shared__ float rs[4], rss[4];
    __shared__ float smean, sinv;
    int wave = tid >> 6, lane = tid & 63;
    if (lane == 0) { rs[wave] = s; rss[wave] = ss; }
    __syncthreads();
    if (tid == 0) {
        float S = rs[0] + rs[1] + rs[2] + rs[3];
        float Q = rss[0] + rss[1] + rss[2] + rss[3];
        float mean = S / N;
        float var = Q / N - mean * mean;
        smean = mean; sinv = rsqrtf(var + EPSF);
    }
    __syncthreads();
    float mean = smean, inv = sinv;
    for (int i = tid; i < N; i += 256) xr[i] = (xr[i] - mean) * inv * w[i];
}

// ---------------------------------------------------------------------------
// Per-token prep: kv_c = LN(kva[:,:512]); k_pe = rope(kva[:,512:]);
// rope q_pe in place inside q (16 heads x 64).
// One block (256 thr) per token row (b*S+s).
// ---------------------------------------------------------------------------
__global__ __launch_bounds__(256) void prep_kernel(
    const float* __restrict__ kva, const float* __restrict__ kvw,
    const float* __restrict__ cosb, const float* __restrict__ sinb,
    float* __restrict__ kvc, float* __restrict__ kpe, float* __restrict__ q)
{
    long long row = blockIdx.x;
    const float* kr = kva + row * (KVLR + ROPED);
    const float* cr = cosb + row * ROPED;
    const float* sr = sinb + row * ROPED;
    int tid = threadIdx.x;
    float v0 = kr[tid], v1 = kr[tid + 256];
    float s = v0 + v1, ss = v0 * v0 + v1 * v1;
#pragma unroll
    for (int off = 32; off > 0; off >>= 1) { s += __shfl_down(s, off); ss += __shfl_down(ss, off); }
    __shared__ float rs[4], rss[4];
    __shared__ float smean, sinv;
    int wave = tid >> 6, lane = tid & 63;
    if (lane == 0) { rs[wave] = s; rss[wave] = ss; }
    __syncthreads();
    if (tid == 0) {
        float S = rs[0] + rs[1] + rs[2] + rs[3];
        float Q = rss[0] + rss[1] + rss[2] + rss[3];
        float mean = S / KVLR;
        float var = Q / KVLR - mean * mean;
        smean = mean; sinv = rsqrtf(var + EPSF);
    }
    __syncthreads();
    float mean = smean, inv = sinv;
    kvc[row * KVLR + tid]       = (v0 - mean) * inv * kvw[tid];
    kvc[row * KVLR + tid + 256] = (v1 - mean) * inv * kvw[tid + 256];
    // k_pe rope (64 dims -> 32 pairs)
    if (tid < 32) {
        float x1 = kr[KVLR + tid], x2 = kr[KVLR + 32 + tid];
        kpe[row * ROPED + tid]      = x1 * cr[tid] - x2 * sr[tid];
        kpe[row * ROPED + 32 + tid] = x2 * cr[32 + tid] + x1 * sr[32 + tid];
    }
    // q_pe rope in place: 16 heads x 32 pairs = 512 items, 2 per thread
    float* qr = q + row * (NHD * QKD);
#pragma unroll
    for (int j = 0; j < 2; ++j) {
        int idx = tid + j * 256;
        int h = idx >> 5, p = idx & 31;
        float* base = qr + h * QKD + NOPE;
        float x1 = base[p], x2 = base[32 + p];
        base[p]      = x1 * cr[p] - x2 * sr[p];
        base[32 + p] = x2 * cr[32 + p] + x1 * sr[32 + p];
    }
}

// ---------------------------------------------------------------------------
// Causal latent attention, one block (256 thr) per (b, h, q) row.
// scores in LDS (<= 1024 floats), block softmax, then ctx accumulation.
// ---------------------------------------------------------------------------
__global__ __launch_bounds__(256) void attn_kernel(
    const float* __restrict__ qlat, const float* __restrict__ q,
    const float* __restrict__ kvc, const float* __restrict__ kpe,
    float* __restrict__ ctx)
{
    int qi = blockIdx.x, h = blockIdx.y, b = blockIdx.z;
    long long row = (long long)b * SS + qi;
    __shared__ float qrow[KVLR];
    __shared__ float qpe[ROPED];
    __shared__ float sc[SS];
    __shared__ float rbuf[4];
    int tid = threadIdx.x;
    qrow[tid]       = qlat[(row * NHD + h) * KVLR + tid];
    qrow[tid + 256] = qlat[(row * NHD + h) * KVLR + tid + 256];
    if (tid < ROPED) qpe[tid] = q[row * (NHD * QKD) + h * QKD + NOPE + tid];
    __syncthreads();
    const float scale = 0.07216878364870323f;  // 1/sqrt(192)
    float lmax = -INFINITY;
    for (int k = tid; k <= qi; k += 256) {
        const float4* kc4 = (const float4*)(kvc + ((long long)b * SS + k) * KVLR);
        const float4* qr4 = (const float4*)qrow;
        float acc = 0.f;
#pragma unroll 4
        for (int i = 0; i < KVLR / 4; ++i) {
            float4 kv = kc4[i]; float4 qv = qr4[i];
            acc += kv.x * qv.x + kv.y * qv.y + kv.z * qv.z + kv.w * qv.w;
        }
        const float4* kp4 = (const float4*)(kpe + ((long long)b * SS + k) * ROPED);
        const float4* qp4 = (const float4*)qpe;
#pragma unroll
        for (int i = 0; i < ROPED / 4; ++i) {
            float4 kv = kp4[i]; float4 qv = qp4[i];
            acc += kv.x * qv.x + kv.y * qv.y + kv.z * qv.z + kv.w * qv.w;
        }
        float sv = acc * scale;
        sc[k] = sv;
        lmax = fmaxf(lmax, sv);
    }
#pragma unroll
    for (int off = 32; off > 0; off >>= 1) lmax = fmaxf(lmax, __shfl_down(lmax, off));
    int wave = tid >> 6, lane = tid & 63;
    if (lane == 0) rbuf[wave] = lmax;
    __syncthreads();
    float m = fmaxf(fmaxf(rbuf[0], rbuf[1]), fmaxf(rbuf[2], rbuf[3]));
    float lsum = 0.f;
    for (int k = tid; k <= qi; k += 256) { float e = __expf(sc[k] - m); sc[k] = e; lsum += e; }
#pragma unroll
    for (int off = 32; off > 0; off >>= 1) lsum += __shfl_down(lsum, off);
    __syncthreads();   // everyone done reading rbuf(max) + all sc writes visible after next barrier
    if (lane == 0) rbuf[wave] = lsum;
    __syncthreads();
    float inv = 1.f / (rbuf[0] + rbuf[1] + rbuf[2] + rbuf[3]);
    // ctx: each thread owns 2 consecutive latent dims (float2-coalesced)
    int l0 = tid * 2;
    float ax = 0.f, ay = 0.f;
    for (int k = 0; k <= qi; ++k) {
        float p = sc[k];
        const float2 kv = *(const float2*)(kvc + ((long long)b * SS + k) * KVLR + l0);
        ax += p * kv.x; ay += p * kv.y;
    }
    float2* outp = (float2*)(ctx + (row * NHD + h) * KVLR + l0);
    *outp = make_float2(ax * inv, ay * inv);
}

// ---------------------------------------------------------------------------
extern "C" void kernel_launch(void* const* d_in, const int* in_sizes, int n_in,
                              void* d_out, int out_size, void* d_ws, size_t ws_size,
                              hipStream_t stream)
{
    const float* hidden    = (const float*)d_in[0];
    const float* cosb      = (const float*)d_in[1];
    const float* sinb      = (const float*)d_in[2];
    const float* w_qa      = (const float*)d_in[3];
    const float* q_a_ln_w  = (const float*)d_in[4];
    const float* w_qb      = (const float*)d_in[5];
    const float* w_kva     = (const float*)d_in[6];
    const float* kv_a_ln_w = (const float*)d_in[7];
    const float* W_UK_T    = (const float*)d_in[8];
    const float* W_UV      = (const float*)d_in[9];
    const float* w_o       = (const float*)d_in[10];
    float* out = (float*)d_out;
    float* ws  = (float*)d_ws;

    const int M = BB * SS;  // 2048 token rows
    // workspace layout (floats); total ~49.5M floats = ~198 MB
    float* qa   = ws;                                   // M*QLR
    float* q    = qa   + (size_t)M * QLR;               // M*NHD*QKD
    float* kva  = q    + (size_t)M * NHD * QKD;         // M*(KVLR+ROPED)
    float* kvc  = kva  + (size_t)M * (KVLR + ROPED);    // M*KVLR
    float* kpe  = kvc  + (size_t)M * KVLR;              // M*ROPED
    float* qlat = kpe  + (size_t)M * ROPED;             // M*NHD*KVLR
    float* ctx  = qlat + (size_t)M * NHD * KVLR;        // M*NHD*KVLR
    float* oh   = ctx  + (size_t)M * NHD * KVLR;        // M*NHD*VDIM

    dim3 blk(256);

    // 1. qa_pre = hidden @ w_qa^T           (2048 x 1536 x 2048)
    gemm_tile<true><<<dim3(QLR / 64, M / 64, 1), blk, 0, stream>>>(
        hidden, w_qa, qa, M, QLR, HH, HH, HH, QLR, 0, 0, 0);
    // 2. qa = LN(qa_pre) * q_a_ln_w
    ln_kernel<<<dim3(M), blk, 0, stream>>>(qa, q_a_ln_w, QLR);
    // 3. q = qa @ w_qb^T                    (2048 x 3072 x 1536)
    gemm_tile<true><<<dim3(NHD * QKD / 64, M / 64, 1), blk, 0, stream>>>(
        qa, w_qb, q, M, NHD * QKD, QLR, QLR, QLR, NHD * QKD, 0, 0, 0);
    // 4. kva = hidden @ w_kva^T             (2048 x 576 x 2048)
    gemm_tile<true><<<dim3((KVLR + ROPED) / 64, M / 64, 1), blk, 0, stream>>>(
        hidden, w_kva, kva, M, KVLR + ROPED, HH, HH, HH, KVLR + ROPED, 0, 0, 0);
    // 5. kv_c = LN(kva[:,:512]); k_pe = rope; q_pe = rope (in place)
    prep_kernel<<<dim3(M), blk, 0, stream>>>(kva, kv_a_ln_w, cosb, sinb, kvc, kpe, q);
    // 6. qlat[h] = q_nope[h] @ W_UK_T[h]    (16 batches of 2048 x 512 x 128)
    gemm_tile<false><<<dim3(KVLR / 64, M / 64, NHD), blk, 0, stream>>>(
        q, W_UK_T, qlat, M, KVLR, NOPE,
        NHD * QKD, KVLR, NHD * KVLR,
        (long long)QKD, (long long)NOPE * KVLR, (long long)KVLR);
    // 7. attention -> ctx
    attn_kernel<<<dim3(SS, NHD, BB), blk, 0, stream>>>(qlat, q, kvc, kpe, ctx);
    // 8. oh[h] = ctx[h] @ W_UV[h]           (16 batches of 2048 x 128 x 512)
    gemm_tile<false><<<dim3(VDIM / 64, M / 64, NHD), blk, 0, stream>>>(
        ctx, W_UV, oh, M, VDIM, KVLR,
        NHD * KVLR, VDIM, NHD * VDIM,
        (long long)KVLR, (long long)KVLR * VDIM, (long long)VDIM);
    // 9. out = oh @ w_o^T                   (2048 x 2048 x 2048)
    gemm_tile<true><<<dim3(HH / 64, M / 64, 1), blk, 0, stream>>>(
        oh, w_o, out, M, HH, NHD * VDIM, NHD * VDIM, NHD * VDIM, HH, 0, 0, 0);
}

// Round 2
// 1855.388 us; speedup vs baseline: 4.1173x; 4.1173x over previous
//
#include <hip/hip_runtime.h>
#include <hip/hip_bf16.h>
#include <math.h>

#define BB 2
#define SS 1024
#define HH 2048
#define NHD 16
#define NOPE 128
#define ROPED 64
#define VDIM 128
#define QKD 192
#define QLR 1536
#define KVLR 512
#define EPSF 1e-5f

typedef __bf16 bf16x8 __attribute__((ext_vector_type(8)));
typedef float  f32x4  __attribute__((ext_vector_type(4)));

// ---------------------------------------------------------------------------
// Generic tiled fp32 GEMM (unchanged from round 1).
//   BT = true :  C = A (M,K) * B^T  with B stored (N,K) row-major
//   BT = false:  C = A (M,K) * B    with B stored (K,N) row-major
// ---------------------------------------------------------------------------
template<bool BT>
__global__ __launch_bounds__(256) void gemm_tile(
    const float* __restrict__ A, const float* __restrict__ B, float* __restrict__ C,
    int M, int N, int K, int lda, int ldb, int ldc,
    long long sA, long long sB, long long sC)
{
    __shared__ float As[16][65];
    __shared__ float Bs[16][65];
    const float* Ab = A + (long long)blockIdx.z * sA;
    const float* Bb = B + (long long)blockIdx.z * sB;
    float*       Cb = C + (long long)blockIdx.z * sC;
    int tid = threadIdx.x;
    int tx = tid & 15, ty = tid >> 4;
    int m0 = blockIdx.y * 64, n0 = blockIdx.x * 64;
    float acc[4][4] = {};
    for (int k0 = 0; k0 < K; k0 += 16) {
#pragma unroll
        for (int i = 0; i < 4; ++i) {
            int e = tid + i * 256;
            int m = e >> 4, k = e & 15;
            As[k][m] = Ab[(long long)(m0 + m) * lda + (k0 + k)];
        }
        if (BT) {
#pragma unroll
            for (int i = 0; i < 4; ++i) {
                int e = tid + i * 256;
                int n = e >> 4, k = e & 15;
                Bs[k][n] = Bb[(long long)(n0 + n) * ldb + (k0 + k)];
            }
        } else {
#pragma unroll
            for (int i = 0; i < 4; ++i) {
                int e = tid + i * 256;
                int k = e >> 6, n = e & 63;
                Bs[k][n] = Bb[(long long)(k0 + k) * ldb + (n0 + n)];
            }
        }
        __syncthreads();
#pragma unroll
        for (int kk = 0; kk < 16; ++kk) {
            float a[4], b[4];
#pragma unroll
            for (int i = 0; i < 4; ++i) a[i] = As[kk][ty * 4 + i];
#pragma unroll
            for (int j = 0; j < 4; ++j) b[j] = Bs[kk][tx * 4 + j];
#pragma unroll
            for (int i = 0; i < 4; ++i)
#pragma unroll
                for (int j = 0; j < 4; ++j)
                    acc[i][j] += a[i] * b[j];
        }
        __syncthreads();
    }
#pragma unroll
    for (int i = 0; i < 4; ++i) {
        long long m = m0 + ty * 4 + i;
#pragma unroll
        for (int j = 0; j < 4; ++j)
            Cb[m * ldc + (n0 + tx * 4 + j)] = acc[i][j];
    }
}

// ---------------------------------------------------------------------------
// In-place LayerNorm over last dim N, weight w. One block per row.
// ---------------------------------------------------------------------------
__global__ __launch_bounds__(256) void ln_kernel(float* __restrict__ x,
                                                 const float* __restrict__ w, int N)
{
    long long row = blockIdx.x;
    float* xr = x + row * N;
    int tid = threadIdx.x;
    float s = 0.f, ss = 0.f;
    for (int i = tid; i < N; i += 256) { float v = xr[i]; s += v; ss += v * v; }
#pragma unroll
    for (int off = 32; off > 0; off >>= 1) { s += __shfl_down(s, off); ss += __shfl_down(ss, off); }
    __shared__ float rs[4], rss[4];
    __shared__ float smean, sinv;
    int wave = tid >> 6, lane = tid & 63;
    if (lane == 0) { rs[wave] = s; rss[wave] = ss; }
    __syncthreads();
    if (tid == 0) {
        float S = rs[0] + rs[1] + rs[2] + rs[3];
        float Q = rss[0] + rss[1] + rss[2] + rss[3];
        float mean = S / N;
        float var = Q / N - mean * mean;
        smean = mean; sinv = rsqrtf(var + EPSF);
    }
    __syncthreads();
    float mean = smean, inv = sinv;
    for (int i = tid; i < N; i += 256) xr[i] = (xr[i] - mean) * inv * w[i];
}

// ---------------------------------------------------------------------------
// Per-token prep: Kc[row] = bf16( concat( LN(kva[:512])*w , rope(kva[512:]) ) )
// and rope q_pe in place inside q (fp32). One block per token row.
// ---------------------------------------------------------------------------
__global__ __launch_bounds__(256) void prep_kernel(
    const float* __restrict__ kva, const float* __restrict__ kvw,
    const float* __restrict__ cosb, const float* __restrict__ sinb,
    __bf16* __restrict__ Kc, float* __restrict__ q)
{
    long long row = blockIdx.x;
    const float* kr = kva + row * (KVLR + ROPED);
    const float* cr = cosb + row * ROPED;
    const float* sr = sinb + row * ROPED;
    int tid = threadIdx.x;
    float v0 = kr[tid], v1 = kr[tid + 256];
    float s = v0 + v1, ss = v0 * v0 + v1 * v1;
#pragma unroll
    for (int off = 32; off > 0; off >>= 1) { s += __shfl_down(s, off); ss += __shfl_down(ss, off); }
    __shared__ float rs[4], rss[4];
    __shared__ float smean, sinv;
    int wave = tid >> 6, lane = tid & 63;
    if (lane == 0) { rs[wave] = s; rss[wave] = ss; }
    __syncthreads();
    if (tid == 0) {
        float S = rs[0] + rs[1] + rs[2] + rs[3];
        float Q = rss[0] + rss[1] + rss[2] + rss[3];
        float mean = S / KVLR;
        float var = Q / KVLR - mean * mean;
        smean = mean; sinv = rsqrtf(var + EPSF);
    }
    __syncthreads();
    float mean = smean, inv = sinv;
    __bf16* kc = Kc + row * 576;
    kc[tid]       = (__bf16)((v0 - mean) * inv * kvw[tid]);
    kc[tid + 256] = (__bf16)((v1 - mean) * inv * kvw[tid + 256]);
    if (tid < 32) {
        float x1 = kr[KVLR + tid], x2 = kr[KVLR + 32 + tid];
        kc[512 + tid]      = (__bf16)(x1 * cr[tid] - x2 * sr[tid]);
        kc[512 + 32 + tid] = (__bf16)(x2 * cr[32 + tid] + x1 * sr[32 + tid]);
    }
    // q_pe rope in place: 16 heads x 32 pairs
    float* qr = q + row * (NHD * QKD);
#pragma unroll
    for (int j = 0; j < 2; ++j) {
        int idx = tid + j * 256;
        int h = idx >> 5, p = idx & 31;
        float* base = qr + h * QKD + NOPE;
        float x1 = base[p], x2 = base[32 + p];
        base[p]      = x1 * cr[p] - x2 * sr[p];
        base[32 + p] = x2 * cr[32 + p] + x1 * sr[32 + p];
    }
}

// ---------------------------------------------------------------------------
// Build Qc bf16 [B][NH][S][576] = concat(qlat[b,s,h,:512], roped q_pe[b,s,h,:64])
// One block per token row (b*S+s).
// ---------------------------------------------------------------------------
__global__ __launch_bounds__(256) void qcast_kernel(
    const float* __restrict__ qlat, const float* __restrict__ q,
    __bf16* __restrict__ Qc)
{
    long long row = blockIdx.x;           // b*S + s
    int b = (int)(row >> 10), s = (int)(row & 1023);
    int tid = threadIdx.x;
    for (int i = tid; i < NHD * 576; i += 256) {
        int h = i / 576, c = i - h * 576;
        float v = (c < 512) ? qlat[row * (NHD * 512) + h * 512 + c]
                            : q[row * (NHD * QKD) + h * QKD + NOPE + (c - 512)];
        Qc[(((size_t)(b * NHD + h)) * SS + s) * 576 + c] = (__bf16)v;
    }
}

// ---------------------------------------------------------------------------
// Flash MLA attention, bf16 MFMA 16x16x32.
// Block: 64 q rows for one (b,h); 4 waves x 16 rows. K-tile = 32 keys.
//   Ks[32][296]  : K' rows, feature-contiguous (staged in 2 chunks of 288)
//   Vs[512][40]  : first 512 features transposed (key-contiguous)
//   Pb[w][16][32]: per-wave P transpose buffer (C-layout -> A-layout)
// MFMA layouts (guide-verified): A[m=lane&15][k=quad*8+j],
// B[k=quad*8+j][n=lane&15], C/D[row=quad*4+reg][col=lane&15].
// ---------------------------------------------------------------------------
__global__ __launch_bounds__(256, 2) void flash_kernel(
    const __bf16* __restrict__ Qc, const __bf16* __restrict__ Kc,
    float* __restrict__ ctx)
{
    __shared__ __bf16 Ks[32][296];     // 18,944 B
    __shared__ __bf16 Vs[512][40];     // 40,960 B
    __shared__ __bf16 Pb[4][16][32];   //  4,096 B   -> 64,000 total
    const int qt = (int)gridDim.x - 1 - (int)blockIdx.x;  // long blocks first
    const int h  = blockIdx.y;
    const int b  = blockIdx.z;
    const int q0 = qt * 64;
    const int tid = threadIdx.x;
    const int w = tid >> 6, lane = tid & 63, quad = lane >> 4, ln = lane & 15;
    const int ktc = q0 / 32 + 2;

    // Q fragments (registers) for this wave's 16 rows
    const size_t qoff = ((size_t)(b * NHD + h) * SS + (size_t)(q0 + w * 16 + ln)) * 576;
    bf16x8 qf[18];
#pragma unroll
    for (int kc = 0; kc < 18; ++kc)
        qf[kc] = *(const bf16x8*)(Qc + qoff + kc * 32 + quad * 8);

    f32x4 O[32];
#pragma unroll
    for (int nt = 0; nt < 32; ++nt) O[nt] = (f32x4){0.f, 0.f, 0.f, 0.f};
    float mrun[4] = {-1e30f, -1e30f, -1e30f, -1e30f};
    float lrun[4] = {0.f, 0.f, 0.f, 0.f};

    const size_t kbase = (size_t)b * SS * 576;
    const float SCL = 0.07216878364870323f * 1.4426950408889634f;  // scale*log2(e)

    for (int kt = 0; kt < ktc; ++kt) {
        const int k0 = kt * 32;
        __syncthreads();                               // prev tile's LDS reads done
        // stage Ks chunk0 (features 0..287) and Vs (features 0..511, transposed)
        for (int i = tid; i < 1152; i += 256) {
            int kk = i / 36, c8 = i - kk * 36;
            *(bf16x8*)&Ks[kk][c8 * 8] =
                *(const bf16x8*)(Kc + kbase + (size_t)(k0 + kk) * 576 + c8 * 8);
        }
        for (int i = tid; i < 2048; i += 256) {
            int kk = i & 31, c8 = i >> 5;   // lanes vary kk -> LDS write ~4-way max
            bf16x8 v = *(const bf16x8*)(Kc + kbase + (size_t)(k0 + kk) * 576 + c8 * 8);
#pragma unroll
            for (int j = 0; j < 8; ++j) Vs[c8 * 8 + j][kk] = v[j];
        }
        __syncthreads();
        f32x4 s0 = (f32x4){0.f, 0.f, 0.f, 0.f};
        f32x4 s1 = (f32x4){0.f, 0.f, 0.f, 0.f};
#pragma unroll
        for (int kc = 0; kc < 9; ++kc) {
            bf16x8 kf0 = *(const bf16x8*)&Ks[ln][kc * 32 + quad * 8];
            bf16x8 kf1 = *(const bf16x8*)&Ks[16 + ln][kc * 32 + quad * 8];
            s0 = __builtin_amdgcn_mfma_f32_16x16x32_bf16(qf[kc], kf0, s0, 0, 0, 0);
            s1 = __builtin_amdgcn_mfma_f32_16x16x32_bf16(qf[kc], kf1, s1, 0, 0, 0);
        }
        __syncthreads();                               // chunk0 reads done
        for (int i = tid; i < 1152; i += 256) {        // stage chunk1 (288..575)
            int kk = i / 36, c8 = i - kk * 36;
            *(bf16x8*)&Ks[kk][c8 * 8] =
                *(const bf16x8*)(Kc + kbase + (size_t)(k0 + kk) * 576 + 288 + c8 * 8);
        }
        __syncthreads();
#pragma unroll
        for (int kc = 0; kc < 9; ++kc) {
            bf16x8 kf0 = *(const bf16x8*)&Ks[ln][kc * 32 + quad * 8];
            bf16x8 kf1 = *(const bf16x8*)&Ks[16 + ln][kc * 32 + quad * 8];
            s0 = __builtin_amdgcn_mfma_f32_16x16x32_bf16(qf[9 + kc], kf0, s0, 0, 0, 0);
            s1 = __builtin_amdgcn_mfma_f32_16x16x32_bf16(qf[9 + kc], kf1, s1, 0, 0, 0);
        }
        // online softmax for this wave's 16 rows
        const bool diag = (k0 + 31 > q0 + w * 16);
        float alpha[4];
#pragma unroll
        for (int r = 0; r < 4; ++r) {
            float v0 = s0[r] * SCL, v1 = s1[r] * SCL;
            if (diag) {
                int qrow = q0 + w * 16 + quad * 4 + r;
                if (k0 + ln > qrow)      v0 = -1e30f;
                if (k0 + 16 + ln > qrow) v1 = -1e30f;
            }
            float mx = fmaxf(v0, v1);
#pragma unroll
            for (int off = 1; off < 16; off <<= 1) mx = fmaxf(mx, __shfl_xor(mx, off));
            float mnew = fmaxf(mrun[r], mx);
            alpha[r] = __builtin_amdgcn_exp2f(mrun[r] - mnew);
            float p0 = __builtin_amdgcn_exp2f(v0 - mnew);
            float p1 = __builtin_amdgcn_exp2f(v1 - mnew);
            float rsum = p0 + p1;
#pragma unroll
            for (int off = 1; off < 16; off <<= 1) rsum += __shfl_xor(rsum, off);
            lrun[r] = lrun[r] * alpha[r] + rsum;
            mrun[r] = mnew;
            Pb[w][quad * 4 + r][ln]      = (__bf16)p0;
            Pb[w][quad * 4 + r][16 + ln] = (__bf16)p1;
        }
#pragma unroll
        for (int nt = 0; nt < 32; ++nt) {
#pragma unroll
            for (int r = 0; r < 4; ++r) O[nt][r] *= alpha[r];
        }
        __syncthreads();                               // P visible / lgkm drained
        bf16x8 pf = *(const bf16x8*)&Pb[w][ln][quad * 8];
#pragma unroll
        for (int nt = 0; nt < 32; ++nt) {
            bf16x8 vf = *(const bf16x8*)&Vs[nt * 16 + ln][quad * 8];
            O[nt] = __builtin_amdgcn_mfma_f32_16x16x32_bf16(pf, vf, O[nt], 0, 0, 0);
        }
    }
    // epilogue: normalize and store fp32 ctx [B,S,NH,512]
#pragma unroll
    for (int r = 0; r < 4; ++r) {
        float inv = 1.f / lrun[r];
        size_t row = (size_t)b * SS + (size_t)(q0 + w * 16 + quad * 4 + r);
        float* op = ctx + (row * NHD + h) * 512;
#pragma unroll
        for (int nt = 0; nt < 32; ++nt)
            op[nt * 16 + ln] = O[nt][r] * inv;
    }
}

// ---------------------------------------------------------------------------
extern "C" void kernel_launch(void* const* d_in, const int* in_sizes, int n_in,
                              void* d_out, int out_size, void* d_ws, size_t ws_size,
                              hipStream_t stream)
{
    const float* hidden    = (const float*)d_in[0];
    const float* cosb      = (const float*)d_in[1];
    const float* sinb      = (const float*)d_in[2];
    const float* w_qa      = (const float*)d_in[3];
    const float* q_a_ln_w  = (const float*)d_in[4];
    const float* w_qb      = (const float*)d_in[5];
    const float* w_kva     = (const float*)d_in[6];
    const float* kv_a_ln_w = (const float*)d_in[7];
    const float* W_UK_T    = (const float*)d_in[8];
    const float* W_UV      = (const float*)d_in[9];
    const float* w_o       = (const float*)d_in[10];
    float* out = (float*)d_out;
    float* ws  = (float*)d_ws;

    const int M = BB * SS;  // 2048 token rows
    // workspace layout: 126.4 MB fp32 + 40.1 MB bf16 = 166.5 MB
    float* qa      = ws;                                  // M*1536
    float* q       = qa      + (size_t)M * QLR;           // M*3072
    float* kva     = q       + (size_t)M * NHD * QKD;     // M*576
    float* ctxqlat = kva     + (size_t)M * (KVLR + ROPED);// M*8192 (qlat, then ctx)
    float* oh      = ctxqlat + (size_t)M * NHD * KVLR;    // M*2048
    __bf16* Kc = (__bf16*)(oh + (size_t)M * NHD * VDIM);  // M*576  bf16
    __bf16* Qc = Kc + (size_t)M * 576;                    // M*9216 bf16

    dim3 blk(256);

    // 1. qa_pre = hidden @ w_qa^T           (2048 x 1536 x 2048)
    gemm_tile<true><<<dim3(QLR / 64, M / 64, 1), blk, 0, stream>>>(
        hidden, w_qa, qa, M, QLR, HH, HH, HH, QLR, 0, 0, 0);
    // 2. qa = LN(qa_pre) * q_a_ln_w
    ln_kernel<<<dim3(M), blk, 0, stream>>>(qa, q_a_ln_w, QLR);
    // 3. q = qa @ w_qb^T                    (2048 x 3072 x 1536)
    gemm_tile<true><<<dim3(NHD * QKD / 64, M / 64, 1), blk, 0, stream>>>(
        qa, w_qb, q, M, NHD * QKD, QLR, QLR, QLR, NHD * QKD, 0, 0, 0);
    // 4. kva = hidden @ w_kva^T             (2048 x 576 x 2048)
    gemm_tile<true><<<dim3((KVLR + ROPED) / 64, M / 64, 1), blk, 0, stream>>>(
        hidden, w_kva, kva, M, KVLR + ROPED, HH, HH, HH, KVLR + ROPED, 0, 0, 0);
    // 5. Kc bf16 = [LN(kv_c), rope(k_pe)]; rope q_pe in place
    prep_kernel<<<dim3(M), blk, 0, stream>>>(kva, kv_a_ln_w, cosb, sinb, Kc, q);
    // 6. qlat[h] = q_nope[h] @ W_UK_T[h]    (16 x [2048 x 512 x 128])
    gemm_tile<false><<<dim3(KVLR / 64, M / 64, NHD), blk, 0, stream>>>(
        q, W_UK_T, ctxqlat, M, KVLR, NOPE,
        NHD * QKD, KVLR, NHD * KVLR,
        (long long)QKD, (long long)NOPE * KVLR, (long long)KVLR);
    // 7. Qc bf16 = concat(qlat, roped q_pe), layout [B,NH,S,576]
    qcast_kernel<<<dim3(M), blk, 0, stream>>>(ctxqlat, q, Qc);
    // 8. flash attention -> ctx (reuses qlat buffer)
    flash_kernel<<<dim3(SS / 64, NHD, BB), blk, 0, stream>>>(Qc, Kc, ctxqlat);
    // 9. oh[h] = ctx[h] @ W_UV[h]           (16 x [2048 x 128 x 512])
    gemm_tile<false><<<dim3(VDIM / 64, M / 64, NHD), blk, 0, stream>>>(
        ctxqlat, W_UV, oh, M, VDIM, KVLR,
        NHD * KVLR, VDIM, NHD * VDIM,
        (long long)KVLR, (long long)KVLR * VDIM, (long long)VDIM);
    // 10. out = oh @ w_o^T                  (2048 x 2048 x 2048)
    gemm_tile<true><<<dim3(HH / 64, M / 64, 1), blk, 0, stream>>>(
        oh, w_o, out, M, HH, NHD * VDIM, NHD * VDIM, NHD * VDIM, HH, 0, 0, 0);
}

// Round 3
// 643.635 us; speedup vs baseline: 11.8688x; 2.8827x over previous
//
#include <hip/hip_runtime.h>
#include <hip/hip_bf16.h>
#include <math.h>

#define BB 2
#define SS 1024
#define HH 2048
#define NHD 16
#define NOPE 128
#define ROPED 64
#define VDIM 128
#define QKD 192
#define QLR 1536
#define KVLR 512
#define EPSF 1e-5f

typedef __bf16 bf16x8 __attribute__((ext_vector_type(8)));
typedef float  f32x4  __attribute__((ext_vector_type(4)));

__device__ __forceinline__ void gload_lds16(const __bf16* g, __bf16* l) {
    __builtin_amdgcn_global_load_lds(
        (const __attribute__((address_space(1))) void*)g,
        (__attribute__((address_space(3))) void*)l, 16, 0, 0);
}

// ---------------------------------------------------------------------------
// MFMA bf16 GEMM: C[M,N] = A[M,K] @ B[N,K]^T, A/B bf16 row-major.
// 128x128 tile, BK=32, global_load_lds width-16 staging (m97 structure).
// OUT_BF16 selects C dtype. Batched over grid.z via element strides sA/sB/sC.
// Requires M%128==0, N%128==0, K%32==0.
// ---------------------------------------------------------------------------
template<bool OUT_BF16>
__global__ __launch_bounds__(256, 2) void gemm_mfma(
    const __bf16* __restrict__ A, const __bf16* __restrict__ B, void* __restrict__ Cv,
    int M, int N, int K, int lda, int ldb, int ldc,
    long long sA, long long sB, long long sC)
{
    __shared__ __bf16 As[128][32];
    __shared__ __bf16 Bs[128][32];
    const __bf16* Ab = A + (long long)blockIdx.z * sA;
    const __bf16* Bb = B + (long long)blockIdx.z * sB;
    const int tid = threadIdx.x;
    const int w = tid >> 6, lane = tid & 63, quad = lane >> 4, ln = lane & 15;
    const int m0 = blockIdx.y * 128, n0 = blockIdx.x * 128;
    const int wm = (w >> 1) * 64, wn = (w & 1) * 64;
    const int srow = tid >> 2, schunk = (tid & 3) * 8;

    f32x4 acc[4][4];
#pragma unroll
    for (int i = 0; i < 4; ++i)
#pragma unroll
        for (int j = 0; j < 4; ++j) acc[i][j] = (f32x4){0.f, 0.f, 0.f, 0.f};

    const __bf16* gA0 = Ab + (size_t)(m0 + srow) * lda + schunk;
    const __bf16* gA1 = gA0 + (size_t)64 * lda;
    const __bf16* gB0 = Bb + (size_t)(n0 + srow) * ldb + schunk;
    const __bf16* gB1 = gB0 + (size_t)64 * ldb;
    __bf16* lA0 = &As[w * 16][0];        // wave-uniform LDS bases
    __bf16* lA1 = &As[64 + w * 16][0];
    __bf16* lB0 = &Bs[w * 16][0];
    __bf16* lB1 = &Bs[64 + w * 16][0];

    for (int k0 = 0; k0 < K; k0 += 32) {
        __syncthreads();                 // prior LDS reads complete
        gload_lds16(gA0 + k0, lA0);
        gload_lds16(gA1 + k0, lA1);
        gload_lds16(gB0 + k0, lB0);
        gload_lds16(gB1 + k0, lB1);
        __syncthreads();                 // staging complete
        bf16x8 af[4], bfr[4];
#pragma unroll
        for (int mi = 0; mi < 4; ++mi)
            af[mi] = *(const bf16x8*)&As[wm + mi * 16 + ln][quad * 8];
#pragma unroll
        for (int ni = 0; ni < 4; ++ni)
            bfr[ni] = *(const bf16x8*)&Bs[wn + ni * 16 + ln][quad * 8];
#pragma unroll
        for (int mi = 0; mi < 4; ++mi)
#pragma unroll
            for (int ni = 0; ni < 4; ++ni)
                acc[mi][ni] = __builtin_amdgcn_mfma_f32_16x16x32_bf16(
                    af[mi], bfr[ni], acc[mi][ni], 0, 0, 0);
    }
    // epilogue: C/D layout col=ln, row=quad*4+r
    if (OUT_BF16) {
        __bf16* Cb = (__bf16*)Cv + (long long)blockIdx.z * sC;
#pragma unroll
        for (int mi = 0; mi < 4; ++mi)
#pragma unroll
            for (int r = 0; r < 4; ++r) {
                size_t row = (size_t)(m0 + wm + mi * 16 + quad * 4 + r);
#pragma unroll
                for (int ni = 0; ni < 4; ++ni)
                    Cb[row * ldc + (n0 + wn + ni * 16 + ln)] = (__bf16)acc[mi][ni][r];
            }
    } else {
        float* Cb = (float*)Cv + (long long)blockIdx.z * sC;
#pragma unroll
        for (int mi = 0; mi < 4; ++mi)
#pragma unroll
            for (int r = 0; r < 4; ++r) {
                size_t row = (size_t)(m0 + wm + mi * 16 + quad * 4 + r);
#pragma unroll
                for (int ni = 0; ni < 4; ++ni)
                    Cb[row * ldc + (n0 + wn + ni * 16 + ln)] = acc[mi][ni][r];
            }
    }
}

// ---------------------------------------------------------------------------
// Cast helpers
// ---------------------------------------------------------------------------
__global__ __launch_bounds__(256) void castf2b(const float* __restrict__ in,
                                               __bf16* __restrict__ out, int n)
{
    int i = (blockIdx.x * 256 + threadIdx.x) * 4;
    if (i < n) {
        float4 v = *(const float4*)(in + i);
        out[i] = (__bf16)v.x; out[i + 1] = (__bf16)v.y;
        out[i + 2] = (__bf16)v.z; out[i + 3] = (__bf16)v.w;
    }
}

// w_kva (576 x 2048) -> bf16 zero-padded to (640 x 2048)
__global__ __launch_bounds__(256) void cast_pad_kva(const float* __restrict__ in,
                                                    __bf16* __restrict__ out)
{
    int idx = (blockIdx.x * 256 + threadIdx.x) * 4;
    int row = idx >> 11, col = idx & 2047;
    if (row < 576) {
        float4 v = *(const float4*)(in + row * 2048 + col);
        out[idx] = (__bf16)v.x; out[idx + 1] = (__bf16)v.y;
        out[idx + 2] = (__bf16)v.z; out[idx + 3] = (__bf16)v.w;
    } else {
        out[idx] = (__bf16)0.f; out[idx + 1] = (__bf16)0.f;
        out[idx + 2] = (__bf16)0.f; out[idx + 3] = (__bf16)0.f;
    }
}

// batched transpose-cast: in[z][R][C] fp32 -> out[z][C][R] bf16
__global__ __launch_bounds__(256) void transpose_cast(const float* __restrict__ in,
                                                      __bf16* __restrict__ out,
                                                      int R, int C)
{
    __shared__ float t[32][33];
    in  += (size_t)blockIdx.z * R * C;
    out += (size_t)blockIdx.z * R * C;
    int c0 = blockIdx.x * 32, r0 = blockIdx.y * 32;
    int tx = threadIdx.x & 31, ty = threadIdx.x >> 5;
#pragma unroll
    for (int i = 0; i < 4; ++i) {
        int r = ty + i * 8;
        t[r][tx] = in[(size_t)(r0 + r) * C + c0 + tx];
    }
    __syncthreads();
#pragma unroll
    for (int i = 0; i < 4; ++i) {
        int rr = ty + i * 8;
        out[(size_t)(c0 + rr) * R + r0 + tx] = (__bf16)t[tx][rr];
    }
}

// ---------------------------------------------------------------------------
// LayerNorm fp32 in -> bf16 out. One block per row.
// ---------------------------------------------------------------------------
__global__ __launch_bounds__(256) void ln_kernel(const float* __restrict__ x,
                                                 const float* __restrict__ w,
                                                 __bf16* __restrict__ y, int N)
{
    long long row = blockIdx.x;
    const float* xr = x + row * N;
    __bf16* yr = y + row * N;
    int tid = threadIdx.x;
    float s = 0.f, ss = 0.f;
    for (int i = tid; i < N; i += 256) { float v = xr[i]; s += v; ss += v * v; }
#pragma unroll
    for (int off = 32; off > 0; off >>= 1) { s += __shfl_down(s, off); ss += __shfl_down(ss, off); }
    __shared__ float rs[4], rss[4];
    __shared__ float smean, sinv;
    int wave = tid >> 6, lane = tid & 63;
    if (lane == 0) { rs[wave] = s; rss[wave] = ss; }
    __syncthreads();
    if (tid == 0) {
        float S = rs[0] + rs[1] + rs[2] + rs[3];
        float Q = rss[0] + rss[1] + rss[2] + rss[3];
        float mean = S / N;
        float var = Q / N - mean * mean;
        smean = mean; sinv = rsqrtf(var + EPSF);
    }
    __syncthreads();
    float mean = smean, inv = sinv;
    for (int i = tid; i < N; i += 256) yr[i] = (__bf16)((xr[i] - mean) * inv * w[i]);
}

// ---------------------------------------------------------------------------
// Per-token prep: Kc[row] = bf16(concat(LN(kva[:512])*w, rope(kva[512:576])))
// (kva row stride 640, padded) and rope q_pe in place inside bf16 q.
// ---------------------------------------------------------------------------
__global__ __launch_bounds__(256) void prep_kernel(
    const float* __restrict__ kva, const float* __restrict__ kvw,
    const float* __restrict__ cosb, const float* __restrict__ sinb,
    __bf16* __restrict__ Kc, __bf16* __restrict__ q)
{
    long long row = blockIdx.x;
    const float* kr = kva + row * 640;
    const float* cr = cosb + row * ROPED;
    const float* sr = sinb + row * ROPED;
    int tid = threadIdx.x;
    float v0 = kr[tid], v1 = kr[tid + 256];
    float s = v0 + v1, ss = v0 * v0 + v1 * v1;
#pragma unroll
    for (int off = 32; off > 0; off >>= 1) { s += __shfl_down(s, off); ss += __shfl_down(ss, off); }
    __shared__ float rs[4], rss[4];
    __shared__ float smean, sinv;
    int wave = tid >> 6, lane = tid & 63;
    if (lane == 0) { rs[wave] = s; rss[wave] = ss; }
    __syncthreads();
    if (tid == 0) {
        float S = rs[0] + rs[1] + rs[2] + rs[3];
        float Q = rss[0] + rss[1] + rss[2] + rss[3];
        float mean = S / KVLR;
        float var = Q / KVLR - mean * mean;
        smean = mean; sinv = rsqrtf(var + EPSF);
    }
    __syncthreads();
    float mean = smean, inv = sinv;
    __bf16* kc = Kc + row * 576;
    kc[tid]       = (__bf16)((v0 - mean) * inv * kvw[tid]);
    kc[tid + 256] = (__bf16)((v1 - mean) * inv * kvw[tid + 256]);
    if (tid < 32) {
        float x1 = kr[KVLR + tid], x2 = kr[KVLR + 32 + tid];
        kc[512 + tid]      = (__bf16)(x1 * cr[tid] - x2 * sr[tid]);
        kc[512 + 32 + tid] = (__bf16)(x2 * cr[32 + tid] + x1 * sr[32 + tid]);
    }
    __bf16* qr = q + row * (NHD * QKD);
#pragma unroll
    for (int j = 0; j < 2; ++j) {
        int idx = tid + j * 256;
        int h = idx >> 5, p = idx & 31;
        __bf16* base = qr + h * QKD + NOPE;
        float x1 = (float)base[p], x2 = (float)base[32 + p];
        base[p]      = (__bf16)(x1 * cr[p] - x2 * sr[p]);
        base[32 + p] = (__bf16)(x2 * cr[32 + p] + x1 * sr[32 + p]);
    }
}

// ---------------------------------------------------------------------------
// Qc bf16 [B][NH][S][576] = concat(qlat_b[b,s,h,:512], roped q_pe bf16)
// ---------------------------------------------------------------------------
__global__ __launch_bounds__(256) void qcast_kernel(
    const __bf16* __restrict__ qlat, const __bf16* __restrict__ qb,
    __bf16* __restrict__ Qc)
{
    long long row = blockIdx.x;           // b*S + s
    int b = (int)(row >> 10), s = (int)(row & 1023);
    int tid = threadIdx.x;
    for (int i = tid; i < NHD * 576; i += 256) {
        int h = i / 576, c = i - h * 576;
        __bf16 v = (c < 512) ? qlat[row * (NHD * 512) + h * 512 + c]
                             : qb[row * (NHD * QKD) + h * QKD + NOPE + (c - 512)];
        Qc[(((size_t)(b * NHD + h)) * SS + s) * 576 + c] = v;
    }
}

// ---------------------------------------------------------------------------
// Flash MLA attention, bf16 MFMA 16x16x32 (validated round 2); ctx out bf16.
// ---------------------------------------------------------------------------
__global__ __launch_bounds__(256, 2) void flash_kernel(
    const __bf16* __restrict__ Qc, const __bf16* __restrict__ Kc,
    __bf16* __restrict__ ctx)
{
    __shared__ __bf16 Ks[32][296];
    __shared__ __bf16 Vs[512][40];
    __shared__ __bf16 Pb[4][16][32];
    const int qt = (int)gridDim.x - 1 - (int)blockIdx.x;  // long blocks first
    const int h  = blockIdx.y;
    const int b  = blockIdx.z;
    const int q0 = qt * 64;
    const int tid = threadIdx.x;
    const int w = tid >> 6, lane = tid & 63, quad = lane >> 4, ln = lane & 15;
    const int ktc = q0 / 32 + 2;

    const size_t qoff = ((size_t)(b * NHD + h) * SS + (size_t)(q0 + w * 16 + ln)) * 576;
    bf16x8 qf[18];
#pragma unroll
    for (int kc = 0; kc < 18; ++kc)
        qf[kc] = *(const bf16x8*)(Qc + qoff + kc * 32 + quad * 8);

    f32x4 O[32];
#pragma unroll
    for (int nt = 0; nt < 32; ++nt) O[nt] = (f32x4){0.f, 0.f, 0.f, 0.f};
    float mrun[4] = {-1e30f, -1e30f, -1e30f, -1e30f};
    float lrun[4] = {0.f, 0.f, 0.f, 0.f};

    const size_t kbase = (size_t)b * SS * 576;
    const float SCL = 0.07216878364870323f * 1.4426950408889634f;

    for (int kt = 0; kt < ktc; ++kt) {
        const int k0 = kt * 32;
        __syncthreads();
        for (int i = tid; i < 1152; i += 256) {
            int kk = i / 36, c8 = i - kk * 36;
            *(bf16x8*)&Ks[kk][c8 * 8] =
                *(const bf16x8*)(Kc + kbase + (size_t)(k0 + kk) * 576 + c8 * 8);
        }
        for (int i = tid; i < 2048; i += 256) {
            int kk = i & 31, c8 = i >> 5;
            bf16x8 v = *(const bf16x8*)(Kc + kbase + (size_t)(k0 + kk) * 576 + c8 * 8);
#pragma unroll
            for (int j = 0; j < 8; ++j) Vs[c8 * 8 + j][kk] = v[j];
        }
        __syncthreads();
        f32x4 s0 = (f32x4){0.f, 0.f, 0.f, 0.f};
        f32x4 s1 = (f32x4){0.f, 0.f, 0.f, 0.f};
#pragma unroll
        for (int kc = 0; kc < 9; ++kc) {
            bf16x8 kf0 = *(const bf16x8*)&Ks[ln][kc * 32 + quad * 8];
            bf16x8 kf1 = *(const bf16x8*)&Ks[16 + ln][kc * 32 + quad * 8];
            s0 = __builtin_amdgcn_mfma_f32_16x16x32_bf16(qf[kc], kf0, s0, 0, 0, 0);
            s1 = __builtin_amdgcn_mfma_f32_16x16x32_bf16(qf[kc], kf1, s1, 0, 0, 0);
        }
        __syncthreads();
        for (int i = tid; i < 1152; i += 256) {
            int kk = i / 36, c8 = i - kk * 36;
            *(bf16x8*)&Ks[kk][c8 * 8] =
                *(const bf16x8*)(Kc + kbase + (size_t)(k0 + kk) * 576 + 288 + c8 * 8);
        }
        __syncthreads();
#pragma unroll
        for (int kc = 0; kc < 9; ++kc) {
            bf16x8 kf0 = *(const bf16x8*)&Ks[ln][kc * 32 + quad * 8];
            bf16x8 kf1 = *(const bf16x8*)&Ks[16 + ln][kc * 32 + quad * 8];
            s0 = __builtin_amdgcn_mfma_f32_16x16x32_bf16(qf[9 + kc], kf0, s0, 0, 0, 0);
            s1 = __builtin_amdgcn_mfma_f32_16x16x32_bf16(qf[9 + kc], kf1, s1, 0, 0, 0);
        }
        const bool diag = (k0 + 31 > q0 + w * 16);
        float alpha[4];
#pragma unroll
        for (int r = 0; r < 4; ++r) {
            float v0 = s0[r] * SCL, v1 = s1[r] * SCL;
            if (diag) {
                int qrow = q0 + w * 16 + quad * 4 + r;
                if (k0 + ln > qrow)      v0 = -1e30f;
                if (k0 + 16 + ln > qrow) v1 = -1e30f;
            }
            float mx = fmaxf(v0, v1);
#pragma unroll
            for (int off = 1; off < 16; off <<= 1) mx = fmaxf(mx, __shfl_xor(mx, off));
            float mnew = fmaxf(mrun[r], mx);
            alpha[r] = __builtin_amdgcn_exp2f(mrun[r] - mnew);
            float p0 = __builtin_amdgcn_exp2f(v0 - mnew);
            float p1 = __builtin_amdgcn_exp2f(v1 - mnew);
            float rsum = p0 + p1;
#pragma unroll
            for (int off = 1; off < 16; off <<= 1) rsum += __shfl_xor(rsum, off);
            lrun[r] = lrun[r] * alpha[r] + rsum;
            mrun[r] = mnew;
            Pb[w][quad * 4 + r][ln]      = (__bf16)p0;
            Pb[w][quad * 4 + r][16 + ln] = (__bf16)p1;
        }
#pragma unroll
        for (int nt = 0; nt < 32; ++nt) {
#pragma unroll
            for (int r = 0; r < 4; ++r) O[nt][r] *= alpha[r];
        }
        __syncthreads();
        bf16x8 pf = *(const bf16x8*)&Pb[w][ln][quad * 8];
#pragma unroll
        for (int nt = 0; nt < 32; ++nt) {
            bf16x8 vf = *(const bf16x8*)&Vs[nt * 16 + ln][quad * 8];
            O[nt] = __builtin_amdgcn_mfma_f32_16x16x32_bf16(pf, vf, O[nt], 0, 0, 0);
        }
    }
#pragma unroll
    for (int r = 0; r < 4; ++r) {
        float inv = 1.f / lrun[r];
        size_t row = (size_t)b * SS + (size_t)(q0 + w * 16 + quad * 4 + r);
        __bf16* op = ctx + (row * NHD + h) * 512;
#pragma unroll
        for (int nt = 0; nt < 32; ++nt)
            op[nt * 16 + ln] = (__bf16)(O[nt][r] * inv);
    }
}

// ---------------------------------------------------------------------------
extern "C" void kernel_launch(void* const* d_in, const int* in_sizes, int n_in,
                              void* d_out, int out_size, void* d_ws, size_t ws_size,
                              hipStream_t stream)
{
    const float* hidden    = (const float*)d_in[0];
    const float* cosb      = (const float*)d_in[1];
    const float* sinb      = (const float*)d_in[2];
    const float* w_qa      = (const float*)d_in[3];
    const float* q_a_ln_w  = (const float*)d_in[4];
    const float* w_qb      = (const float*)d_in[5];
    const float* w_kva     = (const float*)d_in[6];
    const float* kv_a_ln_w = (const float*)d_in[7];
    const float* W_UK_T    = (const float*)d_in[8];
    const float* W_UV      = (const float*)d_in[9];
    const float* w_o       = (const float*)d_in[10];
    float* out = (float*)d_out;

    const int M = BB * SS;  // 2048
    // fp32 region: qa (M*1536) + kva (M*640)  = 17.8 MB
    float* qa  = (float*)d_ws;
    float* kva = qa + (size_t)M * QLR;
    // bf16 region (~174 MB)
    __bf16* Xb    = (__bf16*)(kva + (size_t)M * 640);
    __bf16* qab   = Xb    + (size_t)M * HH;          // M*1536
    __bf16* qb    = qab   + (size_t)M * QLR;         // M*3072
    __bf16* Kc    = qb    + (size_t)M * NHD * QKD;   // M*576
    __bf16* Qc    = Kc    + (size_t)M * 576;         // M*9216
    __bf16* qlatb = Qc    + (size_t)M * NHD * 576;   // M*8192
    __bf16* ctxb  = qlatb + (size_t)M * NHD * KVLR;  // M*8192
    __bf16* ohb   = ctxb  + (size_t)M * NHD * KVLR;  // M*2048
    __bf16* w_qab = ohb   + (size_t)M * HH;          // 1536*2048
    __bf16* w_qbb = w_qab + (size_t)QLR * HH;        // 3072*1536
    __bf16* w_kvb = w_qbb + (size_t)NHD * QKD * QLR; // 640*2048 (padded)
    __bf16* Wkb   = w_kvb + (size_t)640 * HH;        // 16*512*128
    __bf16* Wvb   = Wkb   + (size_t)NHD * KVLR * NOPE;// 16*128*512
    __bf16* w_ob  = Wvb   + (size_t)NHD * VDIM * KVLR;// 2048*2048

    dim3 blk(256);

    // --- casts (bf16 weights + activations) ---
    castf2b<<<dim3((M * HH) / 1024), blk, 0, stream>>>(hidden, Xb, M * HH);
    castf2b<<<dim3((QLR * HH) / 1024), blk, 0, stream>>>(w_qa, w_qab, QLR * HH);
    castf2b<<<dim3((NHD * QKD * QLR) / 1024), blk, 0, stream>>>(w_qb, w_qbb, NHD * QKD * QLR);
    cast_pad_kva<<<dim3((640 * HH) / 1024), blk, 0, stream>>>(w_kva, w_kvb);
    castf2b<<<dim3((HH * HH) / 1024), blk, 0, stream>>>(w_o, w_ob, HH * HH);
    transpose_cast<<<dim3(KVLR / 32, NOPE / 32, NHD), blk, 0, stream>>>(W_UK_T, Wkb, NOPE, KVLR);
    transpose_cast<<<dim3(VDIM / 32, KVLR / 32, NHD), blk, 0, stream>>>(W_UV, Wvb, KVLR, VDIM);

    // 1. qa = Xb @ w_qa^T (fp32 out)        (2048 x 1536 x 2048)
    gemm_mfma<false><<<dim3(QLR / 128, M / 128, 1), blk, 0, stream>>>(
        Xb, w_qab, qa, M, QLR, HH, HH, HH, QLR, 0, 0, 0);
    // 2. qab = bf16(LN(qa))
    ln_kernel<<<dim3(M), blk, 0, stream>>>(qa, q_a_ln_w, qab, QLR);
    // 3. qb = qab @ w_qb^T (bf16 out)       (2048 x 3072 x 1536)
    gemm_mfma<true><<<dim3(NHD * QKD / 128, M / 128, 1), blk, 0, stream>>>(
        qab, w_qbb, qb, M, NHD * QKD, QLR, QLR, QLR, NHD * QKD, 0, 0, 0);
    // 4. kva = Xb @ w_kva^T (fp32, N padded to 640)
    gemm_mfma<false><<<dim3(640 / 128, M / 128, 1), blk, 0, stream>>>(
        Xb, w_kvb, kva, M, 640, HH, HH, HH, 640, 0, 0, 0);
    // 5. Kc = [LN(kv_c), rope(k_pe)] bf16; rope q_pe in place (bf16)
    prep_kernel<<<dim3(M), blk, 0, stream>>>(kva, kv_a_ln_w, cosb, sinb, Kc, qb);
    // 6. qlatb[h] = q_nope[h] @ Wkb[h]^T    (16 x [2048 x 512 x 128])
    gemm_mfma<true><<<dim3(KVLR / 128, M / 128, NHD), blk, 0, stream>>>(
        qb, Wkb, qlatb, M, KVLR, NOPE,
        NHD * QKD, NOPE, NHD * KVLR,
        (long long)QKD, (long long)KVLR * NOPE, (long long)KVLR);
    // 7. Qc = concat(qlatb, roped q_pe), layout [B,NH,S,576]
    qcast_kernel<<<dim3(M), blk, 0, stream>>>(qlatb, qb, Qc);
    // 8. flash attention -> ctx bf16 [B,S,NH*512]
    flash_kernel<<<dim3(SS / 64, NHD, BB), blk, 0, stream>>>(Qc, Kc, ctxb);
    // 9. ohb[h] = ctx[h] @ Wvb[h]^T         (16 x [2048 x 128 x 512])
    gemm_mfma<true><<<dim3(VDIM / 128, M / 128, NHD), blk, 0, stream>>>(
        ctxb, Wvb, ohb, M, VDIM, KVLR,
        NHD * KVLR, KVLR, NHD * VDIM,
        (long long)KVLR, (long long)VDIM * KVLR, (long long)VDIM);
    // 10. out = ohb @ w_o^T (fp32 out)      (2048 x 2048 x 2048)
    gemm_mfma<false><<<dim3(HH / 128, M / 128, 1), blk, 0, stream>>>(
        ohb, w_ob, out, M, HH, NHD * VDIM, NHD * VDIM, NHD * VDIM, HH, 0, 0, 0);
}

// Round 4
// 579.577 us; speedup vs baseline: 13.1806x; 1.1105x over previous
//
#include <hip/hip_runtime.h>
#include <hip/hip_bf16.h>
#include <math.h>

#define BB 2
#define SS 1024
#define HH 2048
#define NHD 16
#define NOPE 128
#define ROPED 64
#define VDIM 128
#define QKD 192
#define QLR 1536
#define KVLR 512
#define EPSF 1e-5f
#define NCOMB 2176   // QLR + 576 kv + 64 pad

typedef __bf16 bf16x8 __attribute__((ext_vector_type(8)));
typedef float  f32x4  __attribute__((ext_vector_type(4)));

__device__ __forceinline__ void gload_lds16(const __bf16* g, __bf16* l) {
    __builtin_amdgcn_global_load_lds(
        (const __attribute__((address_space(1))) void*)g,
        (__attribute__((address_space(3))) void*)l, 16, 0, 0);
}

// ---------------------------------------------------------------------------
// MFMA bf16 GEMM: C[M,N] = A[M,K] @ B[N,K]^T (m97 structure, validated R3).
// ---------------------------------------------------------------------------
template<bool OUT_BF16>
__global__ __launch_bounds__(256, 2) void gemm_mfma(
    const __bf16* __restrict__ A, const __bf16* __restrict__ B, void* __restrict__ Cv,
    int M, int N, int K, int lda, int ldb, int ldc,
    long long sA, long long sB, long long sC)
{
    __shared__ __bf16 As[128][32];
    __shared__ __bf16 Bs[128][32];
    const __bf16* Ab = A + (long long)blockIdx.z * sA;
    const __bf16* Bb = B + (long long)blockIdx.z * sB;
    const int tid = threadIdx.x;
    const int w = tid >> 6, lane = tid & 63, quad = lane >> 4, ln = lane & 15;
    const int m0 = blockIdx.y * 128, n0 = blockIdx.x * 128;
    const int wm = (w >> 1) * 64, wn = (w & 1) * 64;
    const int srow = tid >> 2, schunk = (tid & 3) * 8;

    f32x4 acc[4][4];
#pragma unroll
    for (int i = 0; i < 4; ++i)
#pragma unroll
        for (int j = 0; j < 4; ++j) acc[i][j] = (f32x4){0.f, 0.f, 0.f, 0.f};

    const __bf16* gA0 = Ab + (size_t)(m0 + srow) * lda + schunk;
    const __bf16* gA1 = gA0 + (size_t)64 * lda;
    const __bf16* gB0 = Bb + (size_t)(n0 + srow) * ldb + schunk;
    const __bf16* gB1 = gB0 + (size_t)64 * ldb;
    __bf16* lA0 = &As[w * 16][0];
    __bf16* lA1 = &As[64 + w * 16][0];
    __bf16* lB0 = &Bs[w * 16][0];
    __bf16* lB1 = &Bs[64 + w * 16][0];

    for (int k0 = 0; k0 < K; k0 += 32) {
        __syncthreads();
        gload_lds16(gA0 + k0, lA0);
        gload_lds16(gA1 + k0, lA1);
        gload_lds16(gB0 + k0, lB0);
        gload_lds16(gB1 + k0, lB1);
        __syncthreads();
        bf16x8 af[4], bfr[4];
#pragma unroll
        for (int mi = 0; mi < 4; ++mi)
            af[mi] = *(const bf16x8*)&As[wm + mi * 16 + ln][quad * 8];
#pragma unroll
        for (int ni = 0; ni < 4; ++ni)
            bfr[ni] = *(const bf16x8*)&Bs[wn + ni * 16 + ln][quad * 8];
#pragma unroll
        for (int mi = 0; mi < 4; ++mi)
#pragma unroll
            for (int ni = 0; ni < 4; ++ni)
                acc[mi][ni] = __builtin_amdgcn_mfma_f32_16x16x32_bf16(
                    af[mi], bfr[ni], acc[mi][ni], 0, 0, 0);
    }
    if (OUT_BF16) {
        __bf16* Cb = (__bf16*)Cv + (long long)blockIdx.z * sC;
#pragma unroll
        for (int mi = 0; mi < 4; ++mi)
#pragma unroll
            for (int r = 0; r < 4; ++r) {
                size_t row = (size_t)(m0 + wm + mi * 16 + quad * 4 + r);
#pragma unroll
                for (int ni = 0; ni < 4; ++ni)
                    Cb[row * ldc + (n0 + wn + ni * 16 + ln)] = (__bf16)acc[mi][ni][r];
            }
    } else {
        float* Cb = (float*)Cv + (long long)blockIdx.z * sC;
#pragma unroll
        for (int mi = 0; mi < 4; ++mi)
#pragma unroll
            for (int r = 0; r < 4; ++r) {
                size_t row = (size_t)(m0 + wm + mi * 16 + quad * 4 + r);
#pragma unroll
                for (int ni = 0; ni < 4; ++ni)
                    Cb[row * ldc + (n0 + wn + ni * 16 + ln)] = acc[mi][ni][r];
            }
    }
}

// ---------------------------------------------------------------------------
// Cast helpers
// ---------------------------------------------------------------------------
__global__ __launch_bounds__(256) void castf2b(const float* __restrict__ in,
                                               __bf16* __restrict__ out, int n)
{
    int i = (blockIdx.x * 256 + threadIdx.x) * 4;
    if (i < n) {
        float4 v = *(const float4*)(in + i);
        out[i] = (__bf16)v.x; out[i + 1] = (__bf16)v.y;
        out[i + 2] = (__bf16)v.z; out[i + 3] = (__bf16)v.w;
    }
}

// combined [w_qa(1536); w_kva(576); pad(64)] x 2048 -> bf16
__global__ __launch_bounds__(256) void cast_comb(const float* __restrict__ wqa,
                                                 const float* __restrict__ wkva,
                                                 __bf16* __restrict__ out)
{
    int idx = (blockIdx.x * 256 + threadIdx.x) * 4;
    int row = idx >> 11, col = idx & 2047;
    const float* src;
    if (row < 1536)      src = wqa + (size_t)row * 2048 + col;
    else if (row < 2112) src = wkva + (size_t)(row - 1536) * 2048 + col;
    else {
        out[idx] = (__bf16)0.f; out[idx + 1] = (__bf16)0.f;
        out[idx + 2] = (__bf16)0.f; out[idx + 3] = (__bf16)0.f;
        return;
    }
    float4 v = *(const float4*)src;
    out[idx] = (__bf16)v.x; out[idx + 1] = (__bf16)v.y;
    out[idx + 2] = (__bf16)v.z; out[idx + 3] = (__bf16)v.w;
}

// batched transpose-cast: in[z][R][C] fp32 -> out[z][C][R] bf16
__global__ __launch_bounds__(256) void transpose_cast(const float* __restrict__ in,
                                                      __bf16* __restrict__ out,
                                                      int R, int C)
{
    __shared__ float t[32][33];
    in  += (size_t)blockIdx.z * R * C;
    out += (size_t)blockIdx.z * R * C;
    int c0 = blockIdx.x * 32, r0 = blockIdx.y * 32;
    int tx = threadIdx.x & 31, ty = threadIdx.x >> 5;
#pragma unroll
    for (int i = 0; i < 4; ++i) {
        int r = ty + i * 8;
        t[r][tx] = in[(size_t)(r0 + r) * C + c0 + tx];
    }
    __syncthreads();
#pragma unroll
    for (int i = 0; i < 4; ++i) {
        int rr = ty + i * 8;
        out[(size_t)(c0 + rr) * R + r0 + tx] = (__bf16)t[tx][rr];
    }
}

// Kc[b][k][f<512] bf16 -> Vt[b][f][k] bf16 (key-contiguous V)
__global__ __launch_bounds__(256) void transpose_kc(const __bf16* __restrict__ Kc,
                                                    __bf16* __restrict__ Vt)
{
    __shared__ __bf16 t[32][33];
    int b = blockIdx.z;
    int k0 = blockIdx.x * 32, f0 = blockIdx.y * 32;
    int tx = threadIdx.x & 31, ty = threadIdx.x >> 5;   // ty 0..7
    const __bf16* src = Kc + (size_t)b * SS * 576;
#pragma unroll
    for (int i = 0; i < 4; ++i)
        t[ty + i * 8][tx] = src[(size_t)(k0 + ty + i * 8) * 576 + f0 + tx];
    __syncthreads();
    __bf16* dst = Vt + (size_t)b * 512 * 1024;
#pragma unroll
    for (int i = 0; i < 4; ++i)
        dst[(size_t)(f0 + ty + i * 8) * 1024 + k0 + tx] = t[tx][ty + i * 8];
}

// ---------------------------------------------------------------------------
// LayerNorm fp32 in (row stride ldx) -> bf16 out (row stride N).
// ---------------------------------------------------------------------------
__global__ __launch_bounds__(256) void ln_kernel(const float* __restrict__ x,
                                                 const float* __restrict__ w,
                                                 __bf16* __restrict__ y, int N, int ldx)
{
    long long row = blockIdx.x;
    const float* xr = x + row * ldx;
    __bf16* yr = y + row * N;
    int tid = threadIdx.x;
    float s = 0.f, ss = 0.f;
    for (int i = tid; i < N; i += 256) { float v = xr[i]; s += v; ss += v * v; }
#pragma unroll
    for (int off = 32; off > 0; off >>= 1) { s += __shfl_down(s, off); ss += __shfl_down(ss, off); }
    __shared__ float rs[4], rss[4];
    __shared__ float smean, sinv;
    int wave = tid >> 6, lane = tid & 63;
    if (lane == 0) { rs[wave] = s; rss[wave] = ss; }
    __syncthreads();
    if (tid == 0) {
        float S = rs[0] + rs[1] + rs[2] + rs[3];
        float Q = rss[0] + rss[1] + rss[2] + rss[3];
        float mean = S / N;
        float var = Q / N - mean * mean;
        smean = mean; sinv = rsqrtf(var + EPSF);
    }
    __syncthreads();
    float mean = smean, inv = sinv;
    for (int i = tid; i < N; i += 256) yr[i] = (__bf16)((xr[i] - mean) * inv * w[i]);
}

// ---------------------------------------------------------------------------
// Per-token prep: Kc[row] = bf16(concat(LN(kva[:512])*w, rope(kva[512:576])))
// kva row stride ld; rope q_pe in place inside bf16 q.
// ---------------------------------------------------------------------------
__global__ __launch_bounds__(256) void prep_kernel(
    const float* __restrict__ kva, int ld, const float* __restrict__ kvw,
    const float* __restrict__ cosb, const float* __restrict__ sinb,
    __bf16* __restrict__ Kc, __bf16* __restrict__ q)
{
    long long row = blockIdx.x;
    const float* kr = kva + row * ld;
    const float* cr = cosb + row * ROPED;
    const float* sr = sinb + row * ROPED;
    int tid = threadIdx.x;
    float v0 = kr[tid], v1 = kr[tid + 256];
    float s = v0 + v1, ss = v0 * v0 + v1 * v1;
#pragma unroll
    for (int off = 32; off > 0; off >>= 1) { s += __shfl_down(s, off); ss += __shfl_down(ss, off); }
    __shared__ float rs[4], rss[4];
    __shared__ float smean, sinv;
    int wave = tid >> 6, lane = tid & 63;
    if (lane == 0) { rs[wave] = s; rss[wave] = ss; }
    __syncthreads();
    if (tid == 0) {
        float S = rs[0] + rs[1] + rs[2] + rs[3];
        float Q = rss[0] + rss[1] + rss[2] + rss[3];
        float mean = S / KVLR;
        float var = Q / KVLR - mean * mean;
        smean = mean; sinv = rsqrtf(var + EPSF);
    }
    __syncthreads();
    float mean = smean, inv = sinv;
    __bf16* kc = Kc + row * 576;
    kc[tid]       = (__bf16)((v0 - mean) * inv * kvw[tid]);
    kc[tid + 256] = (__bf16)((v1 - mean) * inv * kvw[tid + 256]);
    if (tid < 32) {
        float x1 = kr[KVLR + tid], x2 = kr[KVLR + 32 + tid];
        kc[512 + tid]      = (__bf16)(x1 * cr[tid] - x2 * sr[tid]);
        kc[512 + 32 + tid] = (__bf16)(x2 * cr[32 + tid] + x1 * sr[32 + tid]);
    }
    __bf16* qr = q + row * (NHD * QKD);
#pragma unroll
    for (int j = 0; j < 2; ++j) {
        int idx = tid + j * 256;
        int h = idx >> 5, p = idx & 31;
        __bf16* base = qr + h * QKD + NOPE;
        float x1 = (float)base[p], x2 = (float)base[32 + p];
        base[p]      = (__bf16)(x1 * cr[p] - x2 * sr[p]);
        base[32 + p] = (__bf16)(x2 * cr[32 + p] + x1 * sr[32 + p]);
    }
}

// ---------------------------------------------------------------------------
// Qc bf16 [B][NH][S][576] = concat(qlat_b, roped q_pe bf16)
// ---------------------------------------------------------------------------
__global__ __launch_bounds__(256) void qcast_kernel(
    const __bf16* __restrict__ qlat, const __bf16* __restrict__ qb,
    __bf16* __restrict__ Qc)
{
    long long row = blockIdx.x;           // b*S + s
    int b = (int)(row >> 10), s = (int)(row & 1023);
    int tid = threadIdx.x;
    for (int i = tid; i < NHD * 576; i += 256) {
        int h = i / 576, c = i - h * 576;
        __bf16 v = (c < 512) ? qlat[row * (NHD * 512) + h * 512 + c]
                             : qb[row * (NHD * QKD) + h * QKD + NOPE + (c - 512)];
        Qc[(((size_t)(b * NHD + h)) * SS + s) * 576 + c] = v;
    }
}

// ---------------------------------------------------------------------------
// Flash MLA v3: single-stage Ks[32][584] (full 576 feats), Vs[512][36] staged
// vectorized from pre-transposed Vt, 2 barriers per 32-key tile.
// ---------------------------------------------------------------------------
__global__ __launch_bounds__(256, 2) void flash_kernel(
    const __bf16* __restrict__ Qc, const __bf16* __restrict__ Kc,
    const __bf16* __restrict__ Vt, __bf16* __restrict__ ctx)
{
    __shared__ __bf16 Ks[32][584];     // 37,376 B (pad: 2-way-free reads)
    __shared__ __bf16 Vs[512][36];     // 36,864 B (stride 18 words: 2-way-free)
    __shared__ __bf16 Pb[4][16][32];   //  4,096 B  -> 78,336 total (2 blocks/CU)
    const int qt = (int)gridDim.x - 1 - (int)blockIdx.x;  // long blocks first
    const int h  = blockIdx.y;
    const int b  = blockIdx.z;
    const int q0 = qt * 64;
    const int tid = threadIdx.x;
    const int w = tid >> 6, lane = tid & 63, quad = lane >> 4, ln = lane & 15;
    const int ktc = q0 / 32 + 2;

    const size_t qoff = ((size_t)(b * NHD + h) * SS + (size_t)(q0 + w * 16 + ln)) * 576;
    bf16x8 qf[18];
#pragma unroll
    for (int kc = 0; kc < 18; ++kc)
        qf[kc] = *(const bf16x8*)(Qc + qoff + kc * 32 + quad * 8);

    f32x4 O[32];
#pragma unroll
    for (int nt = 0; nt < 32; ++nt) O[nt] = (f32x4){0.f, 0.f, 0.f, 0.f};
    float mrun[4] = {-1e30f, -1e30f, -1e30f, -1e30f};
    float lrun[4] = {0.f, 0.f, 0.f, 0.f};

    const size_t kbase = (size_t)b * SS * 576;
    const size_t vbase = (size_t)b * 512 * 1024;
    const float SCL = 0.07216878364870323f * 1.4426950408889634f;

    // staging index maps (all vectorized b128, bank-uniform)
    const int krow = tid >> 3, kc0 = (tid & 7) * 8;   // Ks: 9 chunks/thread
    const int vf0 = tid >> 2, vk0 = (tid & 3) * 8;    // Vs: 8 chunks/thread

    for (int kt = 0; kt < ktc; ++kt) {
        const int k0 = kt * 32;
        __syncthreads();                               // prev tile's LDS reads done
        const __bf16* kg = Kc + kbase + (size_t)(k0 + krow) * 576 + kc0;
#pragma unroll
        for (int i = 0; i < 9; ++i)
            *(bf16x8*)&Ks[krow][kc0 + i * 64] = *(const bf16x8*)(kg + i * 64);
        const __bf16* vg = Vt + vbase + (size_t)vf0 * 1024 + k0 + vk0;
#pragma unroll
        for (int i = 0; i < 8; ++i)
            *(bf16x8*)&Vs[vf0 + i * 64][vk0] = *(const bf16x8*)(vg + (size_t)(i * 64) * 1024);
        __syncthreads();                               // staging complete

        f32x4 s0 = (f32x4){0.f, 0.f, 0.f, 0.f};
        f32x4 s1 = (f32x4){0.f, 0.f, 0.f, 0.f};
#pragma unroll
        for (int kc = 0; kc < 18; ++kc) {
            bf16x8 kf0 = *(const bf16x8*)&Ks[ln][kc * 32 + quad * 8];
            bf16x8 kf1 = *(const bf16x8*)&Ks[16 + ln][kc * 32 + quad * 8];
            s0 = __builtin_amdgcn_mfma_f32_16x16x32_bf16(qf[kc], kf0, s0, 0, 0, 0);
            s1 = __builtin_amdgcn_mfma_f32_16x16x32_bf16(qf[kc], kf1, s1, 0, 0, 0);
        }

        const bool diag = (k0 + 31 > q0 + w * 16);
        float alpha[4];
#pragma unroll
        for (int r = 0; r < 4; ++r) {
            float v0 = s0[r] * SCL, v1 = s1[r] * SCL;
            if (diag) {
                int qrow = q0 + w * 16 + quad * 4 + r;
                if (k0 + ln > qrow)      v0 = -1e30f;
                if (k0 + 16 + ln > qrow) v1 = -1e30f;
            }
            float mx = fmaxf(v0, v1);
#pragma unroll
            for (int off = 1; off < 16; off <<= 1) mx = fmaxf(mx, __shfl_xor(mx, off));
            float mnew = fmaxf(mrun[r], mx);
            alpha[r] = __builtin_amdgcn_exp2f(mrun[r] - mnew);
            float p0 = __builtin_amdgcn_exp2f(v0 - mnew);
            float p1 = __builtin_amdgcn_exp2f(v1 - mnew);
            float rsum = p0 + p1;
#pragma unroll
            for (int off = 1; off < 16; off <<= 1) rsum += __shfl_xor(rsum, off);
            lrun[r] = lrun[r] * alpha[r] + rsum;
            mrun[r] = mnew;
            Pb[w][quad * 4 + r][ln]      = (__bf16)p0;
            Pb[w][quad * 4 + r][16 + ln] = (__bf16)p1;
        }
#pragma unroll
        for (int nt = 0; nt < 32; ++nt) {
#pragma unroll
            for (int r = 0; r < 4; ++r) O[nt][r] *= alpha[r];
        }
        bf16x8 pf = *(const bf16x8*)&Pb[w][ln][quad * 8];  // per-wave, no barrier
#pragma unroll
        for (int nt = 0; nt < 32; ++nt) {
            bf16x8 vf = *(const bf16x8*)&Vs[nt * 16 + ln][quad * 8];
            O[nt] = __builtin_amdgcn_mfma_f32_16x16x32_bf16(pf, vf, O[nt], 0, 0, 0);
        }
    }
#pragma unroll
    for (int r = 0; r < 4; ++r) {
        float inv = 1.f / lrun[r];
        size_t row = (size_t)b * SS + (size_t)(q0 + w * 16 + quad * 4 + r);
        __bf16* op = ctx + (row * NHD + h) * 512;
#pragma unroll
        for (int nt = 0; nt < 32; ++nt)
            op[nt * 16 + ln] = (__bf16)(O[nt][r] * inv);
    }
}

// ---------------------------------------------------------------------------
extern "C" void kernel_launch(void* const* d_in, const int* in_sizes, int n_in,
                              void* d_out, int out_size, void* d_ws, size_t ws_size,
                              hipStream_t stream)
{
    const float* hidden    = (const float*)d_in[0];
    const float* cosb      = (const float*)d_in[1];
    const float* sinb      = (const float*)d_in[2];
    const float* w_qa      = (const float*)d_in[3];
    const float* q_a_ln_w  = (const float*)d_in[4];
    const float* w_qb      = (const float*)d_in[5];
    const float* w_kva     = (const float*)d_in[6];
    const float* kv_a_ln_w = (const float*)d_in[7];
    const float* W_UK_T    = (const float*)d_in[8];
    const float* W_UV      = (const float*)d_in[9];
    const float* w_o       = (const float*)d_in[10];
    float* out = (float*)d_out;

    const int M = BB * SS;  // 2048
    // fp32: combined qa|kva activation (M x 2176) = 17.8 MB
    float* qakva = (float*)d_ws;
    // bf16 region
    __bf16* Xb    = (__bf16*)(qakva + (size_t)M * NCOMB);
    __bf16* qab   = Xb    + (size_t)M * HH;           // M*1536
    __bf16* qb    = qab   + (size_t)M * QLR;          // M*3072
    __bf16* Kc    = qb    + (size_t)M * NHD * QKD;    // M*576
    __bf16* Qc    = Kc    + (size_t)M * 576;          // M*9216
    __bf16* qlatb = Qc    + (size_t)M * NHD * 576;    // M*8192
    __bf16* ctxb  = qlatb + (size_t)M * NHD * KVLR;   // M*8192
    __bf16* ohb   = ctxb  + (size_t)M * NHD * KVLR;   // M*2048
    __bf16* Vt    = ohb   + (size_t)M * HH;           // 2*512*1024
    __bf16* w_cmb = Vt    + (size_t)BB * 512 * SS;    // 2176*2048
    __bf16* w_qbb = w_cmb + (size_t)NCOMB * HH;       // 3072*1536
    __bf16* Wkb   = w_qbb + (size_t)NHD * QKD * QLR;  // 16*512*128
    __bf16* Wvb   = Wkb   + (size_t)NHD * KVLR * NOPE;// 16*128*512
    __bf16* w_ob  = Wvb   + (size_t)NHD * VDIM * KVLR;// 2048*2048

    dim3 blk(256);

    // --- casts ---
    castf2b<<<dim3((M * HH) / 1024), blk, 0, stream>>>(hidden, Xb, M * HH);
    cast_comb<<<dim3((NCOMB * HH) / 1024), blk, 0, stream>>>(w_qa, w_kva, w_cmb);
    castf2b<<<dim3((NHD * QKD * QLR) / 1024), blk, 0, stream>>>(w_qb, w_qbb, NHD * QKD * QLR);
    castf2b<<<dim3((HH * HH) / 1024), blk, 0, stream>>>(w_o, w_ob, HH * HH);
    transpose_cast<<<dim3(KVLR / 32, NOPE / 32, NHD), blk, 0, stream>>>(W_UK_T, Wkb, NOPE, KVLR);
    transpose_cast<<<dim3(VDIM / 32, KVLR / 32, NHD), blk, 0, stream>>>(W_UV, Wvb, KVLR, VDIM);

    // 1+4 fused: qakva = Xb @ [w_qa; w_kva]^T   (2048 x 2176 x 2048)
    gemm_mfma<false><<<dim3(NCOMB / 128, M / 128, 1), blk, 0, stream>>>(
        Xb, w_cmb, qakva, M, NCOMB, HH, HH, HH, NCOMB, 0, 0, 0);
    // 2. qab = bf16(LN(qakva[:, :1536]))
    ln_kernel<<<dim3(M), blk, 0, stream>>>(qakva, q_a_ln_w, qab, QLR, NCOMB);
    // 3. qb = qab @ w_qb^T (bf16)              (2048 x 3072 x 1536)
    gemm_mfma<true><<<dim3(NHD * QKD / 128, M / 128, 1), blk, 0, stream>>>(
        qab, w_qbb, qb, M, NHD * QKD, QLR, QLR, QLR, NHD * QKD, 0, 0, 0);
    // 5. Kc = [LN(kv_c), rope(k_pe)] bf16; rope q_pe in place (bf16)
    prep_kernel<<<dim3(M), blk, 0, stream>>>(qakva + QLR, NCOMB, kv_a_ln_w,
                                             cosb, sinb, Kc, qb);
    // 5b. Vt = transpose(Kc[:, :512])
    transpose_kc<<<dim3(SS / 32, 512 / 32, BB), blk, 0, stream>>>(Kc, Vt);
    // 6. qlatb[h] = q_nope[h] @ Wkb[h]^T       (16 x [2048 x 512 x 128])
    gemm_mfma<true><<<dim3(KVLR / 128, M / 128, NHD), blk, 0, stream>>>(
        qb, Wkb, qlatb, M, KVLR, NOPE,
        NHD * QKD, NOPE, NHD * KVLR,
        (long long)QKD, (long long)KVLR * NOPE, (long long)KVLR);
    // 7. Qc = concat(qlatb, roped q_pe), layout [B,NH,S,576]
    qcast_kernel<<<dim3(M), blk, 0, stream>>>(qlatb, qb, Qc);
    // 8. flash attention -> ctx bf16 [B,S,NH*512]
    flash_kernel<<<dim3(SS / 64, NHD, BB), blk, 0, stream>>>(Qc, Kc, Vt, ctxb);
    // 9. ohb[h] = ctx[h] @ Wvb[h]^T            (16 x [2048 x 128 x 512])
    gemm_mfma<true><<<dim3(VDIM / 128, M / 128, NHD), blk, 0, stream>>>(
        ctxb, Wvb, ohb, M, VDIM, KVLR,
        NHD * KVLR, KVLR, NHD * VDIM,
        (long long)KVLR, (long long)VDIM * KVLR, (long long)VDIM);
    // 10. out = ohb @ w_o^T (fp32)             (2048 x 2048 x 2048)
    gemm_mfma<false><<<dim3(HH / 128, M / 128, 1), blk, 0, stream>>>(
        ohb, w_ob, out, M, HH, NHD * VDIM, NHD * VDIM, NHD * VDIM, HH, 0, 0, 0);
}